// Round 9
// baseline (250.472 us; speedup 1.0000x reference)
//
#include <hip/hip_runtime.h>
#include <stdint.h>

#define INP 128
#define OUTD 128
#define WT_STRIDE 136    // k-stride (bf16 elems) for W' rows: +8 pad, keeps ds_read_b128 16B-aligned
#define XT_STRIDE 136    // bf16 elems per x-tile row (272 B, 16B-aligned frag reads)
#define BB_STRIDE 272    // bounce row stride in BYTES (= 136 bf16) — same footprint as x-stage
#define BUF_BYTES 4352   // per-wave union buffer: x-stage 16*136*2 == bounce 16*272

typedef __bf16 bf16x8 __attribute__((ext_vector_type(8)));
typedef __bf16 bf16x4 __attribute__((ext_vector_type(4)));
typedef float  floatx4 __attribute__((ext_vector_type(4)));
typedef bf16x8 __attribute__((may_alias)) bf16x8_a;
typedef bf16x4 __attribute__((may_alias)) bf16x4_a;

// ---------------- threefry2x32 (bit-exact vs jax._src.prng) ----------------
__device__ __forceinline__ uint32_t rotl32(uint32_t v, uint32_t n) {
  return (v << n) | (v >> (32u - n));
}
__device__ __forceinline__ void tf_round(uint32_t& x0, uint32_t& x1, uint32_t r) {
  x0 += x1; x1 = rotl32(x1, r); x1 ^= x0;
}
__device__ void threefry2x32(uint32_t k0, uint32_t k1, uint32_t c0, uint32_t c1,
                             uint32_t& o0, uint32_t& o1) {
  uint32_t k2 = k0 ^ k1 ^ 0x1BD11BDAu;
  uint32_t x0 = c0 + k0, x1 = c1 + k1;
  tf_round(x0,x1,13); tf_round(x0,x1,15); tf_round(x0,x1,26); tf_round(x0,x1,6);
  x0 += k1; x1 += k2 + 1u;
  tf_round(x0,x1,17); tf_round(x0,x1,29); tf_round(x0,x1,16); tf_round(x0,x1,24);
  x0 += k2; x1 += k0 + 2u;
  tf_round(x0,x1,13); tf_round(x0,x1,15); tf_round(x0,x1,26); tf_round(x0,x1,6);
  x0 += k0; x1 += k1 + 3u;
  tf_round(x0,x1,17); tf_round(x0,x1,29); tf_round(x0,x1,16); tf_round(x0,x1,24);
  x0 += k1; x1 += k2 + 4u;
  tf_round(x0,x1,13); tf_round(x0,x1,15); tf_round(x0,x1,26); tf_round(x0,x1,6);
  x0 += k2; x1 += k0 + 5u;
  o0 = x0; o1 = x1;
}

// Giles single-precision erfinv (matches XLA ErfInv32 family; ~1e-6 abs err)
__device__ float erfinv_giles(float x) {
  float w = -logf((1.0f - x) * (1.0f + x));
  float p;
  if (w < 5.0f) {
    w = w - 2.5f;
    p = 2.81022636e-08f;
    p = fmaf(p, w, 3.43273939e-07f);
    p = fmaf(p, w, -3.5233877e-06f);
    p = fmaf(p, w, -4.39150654e-06f);
    p = fmaf(p, w, 0.00021858087f);
    p = fmaf(p, w, -0.00125372503f);
    p = fmaf(p, w, -0.00417768164f);
    p = fmaf(p, w, 0.246640727f);
    p = fmaf(p, w, 1.50140941f);
  } else {
    w = sqrtf(w) - 3.0f;
    p = -0.000200214257f;
    p = fmaf(p, w, 0.000100950558f);
    p = fmaf(p, w, 0.00134934322f);
    p = fmaf(p, w, -0.00367342844f);
    p = fmaf(p, w, 0.00573950773f);
    p = fmaf(p, w, -0.0076224613f);
    p = fmaf(p, w, 0.00943887047f);
    p = fmaf(p, w, 1.00167406f);
    p = fmaf(p, w, 2.83297682f);
  }
  return p * x;
}

__device__ float normal_from_bits(uint32_t bits) {
  const float lo = -0.999999940395355224609375f;
  uint32_t fb = (bits >> 9) | 0x3F800000u;
  float f = __uint_as_float(fb) - 1.0f;
  float u = fmaxf(lo, f * 2.0f + lo);
  return 1.41421356237309515f * erfinv_giles(u);
}

// partitionable-threefry path (verified bit-exact in earlier rounds)
__device__ __forceinline__ uint32_t rand_bits(uint32_t ka, uint32_t kb, int i) {
  uint32_t o0, o1;
  threefry2x32(ka, kb, 0u, (uint32_t)i, o0, o1);
  return o0 ^ o1;
}

// ---------------- fused setup: one launch, 64 blocks x 256 ----------------
__global__ __launch_bounds__(256) void setup_fused(
    const float* __restrict__ w, const float* __restrict__ bias,
    __bf16* __restrict__ wt, float* __restrict__ biasEff) {
  __shared__ float red[8];
  const int tid = threadIdx.x;

  const floatx4* w4 = (const floatx4*)w;
  float m0 = -3.4e38f, m1 = m0, m2 = m0, m3 = m0;
  #pragma unroll
  for (int it = 0; it < 16; ++it) {
    floatx4 v = w4[it * 256 + tid];
    m0 = fmaxf(m0, v[0]); m1 = fmaxf(m1, v[1]);
    m2 = fmaxf(m2, v[2]); m3 = fmaxf(m3, v[3]);
  }
  float m = fmaxf(fmaxf(m0, m1), fmaxf(m2, m3));
  #pragma unroll
  for (int off = 1; off < 64; off <<= 1) m = fmaxf(m, __shfl_xor(m, off));
  if ((tid & 63) == 0) red[tid >> 6] = m;
  __syncthreads();
  const float wmax = fmaxf(fmaxf(red[0], red[1]), fmaxf(red[2], red[3]));

  // weight noise + quant for this block's 256 weights
  uint32_t k1a, k1b;
  threefry2x32(0u, 1234u, 0u, 0u, k1a, k1b);
  const int i = blockIdx.x * 256 + tid;
  float nrm = normal_from_bits(rand_bits(k1a, k1b, i));
  int r = i >> 7, c = i & 127;   // w[r][c]: r = k (input dim), c = n (output dim)
  float wv = w[i];
  float wq = rintf(fminf(fmaxf(wv * 128.f, -127.f), 127.f)) * 0.0078125f;
  wt[c * WT_STRIDE + r] = (__bf16)(wq + (nrm * wmax) * 0.1f);

  // block 0 (uniform branch): bias max + biasEff
  if (blockIdx.x == 0) {
    float bv = (tid < OUTD) ? bias[tid] : -3.4e38f;
    float bm = bv;
    #pragma unroll
    for (int off = 1; off < 64; off <<= 1) bm = fmaxf(bm, __shfl_xor(bm, off));
    if ((tid & 63) == 0) red[4 + (tid >> 6)] = bm;
    __syncthreads();
    const float bmax = fmaxf(fmaxf(red[4], red[5]), fmaxf(red[6], red[7]));
    if (tid < OUTD) {
      uint32_t k2a, k2b;
      threefry2x32(0u, 1234u, 0u, 1u, k2a, k2b);
      float nrm2 = normal_from_bits(rand_bits(k2a, k2b, tid));
      float bq = rintf(fminf(fmaxf(bv * 128.f, -127.f), 127.f)) * 0.0078125f;
      biasEff[tid] = bq + (nrm2 * bmax) * 0.1f;
    }
  }
}

// ---------------- main ----------------
// R16 = R15 + NON-TEMPORAL full-line output stores. Evidence through R15:
// clean useful-byte rate pins at 2.3-2.4 TB/s regardless of waves (8 or 12
// per CU), prefetch depth (1-3), or pipelining style — and per-iteration
// cadence ~33k cycles matches one full 8KB store-drain per wave per
// iteration at the observed 1.56 TB/s HBM write rate. Mechanism: vmcnt is a
// SINGLE in-order counter for loads AND stores, so any wait for the next
// tile's loads must first retire the previous tile's stores; store acks
// queue behind L2 write-allocate/eviction churn (131MB streamed through a
// 32MB L2). Fix: nt stores skip allocation and stream out, making acks
// cheap. Unlike R9 (nt on 64-B half-lines -> broke merging), R15's bounce
// made every store cover 8 FULL 128-B lines — nt cannot create RMW here.
// Watch: WRITE_SIZE must stay exactly 131072 KB.
__device__ __forceinline__ void load_tile_asm(floatx4 v[8], const float* __restrict__ x,
                                              long tile, int lane) {
  const float* p = x + ((size_t)tile << 11) + lane * 4;   // tile*2048 floats
  #pragma unroll
  for (int k = 0; k < 8; ++k) {
    asm volatile("global_load_dwordx4 %0, %1, off"
                 : "=v"(v[k])
                 : "v"((uint64_t)(uintptr_t)(p + k * 256)));
  }
}

#define WAIT_VMCNT(N) do { \
    asm volatile("s_waitcnt vmcnt(" #N ")"); \
    __builtin_amdgcn_sched_barrier(0); \
  } while (0)

// quantize + deposit bf16: instr k holds rows {2k,2k+1}; lane i -> row 2k+(i>>5), col (i&31)*4
// `kick` is 0 at runtime (asm-produced) — WAR data-dep vs prev tile's bounce reads.
__device__ __forceinline__ void stage_tile_q(const floatx4 v[8], __bf16* __restrict__ myX,
                                             int lane, float s1, float r1, uint32_t kick) {
  const int r0 = lane >> 5;
  const int c  = (lane & 31) * 4 + (int)kick;
  #pragma unroll
  for (int k = 0; k < 8; ++k) {
    bf16x4 q;
    #pragma unroll
    for (int j = 0; j < 4; ++j)
      q[j] = (__bf16)(rintf(fminf(fmaxf(v[k][j] * s1, -127.f), 127.f)) * r1);
    *(bf16x4_a*)&myX[(2 * k + r0) * XT_STRIDE + c] = q;
  }
}

__device__ __forceinline__ uint32_t compute_store_tile(
    const __bf16* __restrict__ myX, uint32_t bounceBase,
    const __bf16* sW, const float* sBias,
    float* __restrict__ out, long tile, int lane, int n16, int quad,
    float s2, float r2) {
  floatx4 acc[8];
  #pragma unroll
  for (int ct = 0; ct < 8; ++ct) acc[ct] = (floatx4)0.0f;

  #pragma unroll
  for (int kc = 0; kc < 4; ++kc) {
    const int kOff = kc * 32 + quad * 8;
    bf16x8 a = *(const bf16x8_a*)&myX[n16 * XT_STRIDE + kOff];   // ds_read_b128, pre-quantized
    #pragma unroll
    for (int ct = 0; ct < 8; ++ct) {
      bf16x8 wfrag = *(const bf16x8*)&sW[(ct * 16 + n16) * WT_STRIDE + kOff];
      // swapped operands: D[i=outcol][j=batchrow] (transposed C/D)
      acc[ct] = __builtin_amdgcn_mfma_f32_16x16x32_bf16(wfrag, a, acc[ct], 0, 0, 0);
    }
  }

  // bias + quant to integer code k in [-127,127]; pack bf16x4 per ct (exact)
  bf16x4 d[8];
  #pragma unroll
  for (int ct = 0; ct < 8; ++ct) {
    const int colBase = ct * 16 + quad * 4;
    #pragma unroll
    for (int r = 0; r < 4; ++r) {
      float h = acc[ct][r] + sBias[colBase + r];
      d[ct][r] = (__bf16)rintf(fminf(fmaxf(h * s2, -127.0f), 127.0f));
    }
  }

  // bounce writes: element (row=n16, col=ct*16+quad*4+r) at row*272 + col*2
  const uint32_t wbase = bounceBase + (uint32_t)n16 * BB_STRIDE + (uint32_t)quad * 8u;
  #pragma unroll
  for (int ct = 0; ct < 8; ++ct)
    asm volatile("ds_write_b64 %0, %1" :: "v"(wbase + (uint32_t)(ct * 32)), "v"(d[ct]));

  // bounce reads: chunk j covers rows {2j,2j+1}; lane i -> row 2j+(i>>5), col (i&31)*4
  const uint32_t rbase = bounceBase + (uint32_t)((lane >> 5) * BB_STRIDE + (lane & 31) * 8);
  bf16x4 rr[8];
  #pragma unroll
  for (int j = 0; j < 8; ++j)
    asm volatile("ds_read_b64 %0, %1" : "=&v"(rr[j]) : "v"(rbase + (uint32_t)(j * 2 * BB_STRIDE)));
  asm volatile("s_waitcnt lgkmcnt(0)");
  __builtin_amdgcn_sched_barrier(0);   // consumers must not hoist above the wait
  // keep write-source regs alive until all bounce ops processed
  asm volatile("" :: "v"(d[0]), "v"(d[1]), "v"(d[2]), "v"(d[3]),
                     "v"(d[4]), "v"(d[5]), "v"(d[6]), "v"(d[7]));

  // lane-contiguous full-line stores: 8 x 1KB per tile (8 full 128-B lines
  // each), NON-TEMPORAL: no L2 allocation -> cheap store acks, no churn.
  float* outp = out + ((size_t)tile << 11);
  #pragma unroll
  for (int j = 0; j < 8; ++j) {
    floatx4 o;
    #pragma unroll
    for (int q = 0; q < 4; ++q) o[q] = (float)rr[j][q] * r2;
    __builtin_nontemporal_store(o, (floatx4*)(outp + j * 256 + lane * 4));
  }

  uint32_t kick;
  asm volatile("v_mov_b32 %0, 0" : "=v"(kick));   // opaque 0, ordered after reads
  return kick;
}

// 3 waves/EU -> 3 blocks/CU at 52736 B LDS; VGPR cap 170
__global__ __launch_bounds__(256, 3) void linlayer_main(
    const float* __restrict__ x, const __bf16* __restrict__ wt,
    const float* __restrict__ biasEff, const float* __restrict__ a1p,
    const float* __restrict__ a2p, float* __restrict__ out, int nTiles) {
  __shared__ __attribute__((aligned(16))) __bf16 sW[OUTD * WT_STRIDE];   // 34816 B
  __shared__ __attribute__((aligned(16))) char  sBuf[4][BUF_BYTES];      // 17408 B (x-stage ∪ out-bounce)
  __shared__ float sBias[OUTD];                                          //   512 B

  const int tid  = threadIdx.x;
  const int wave = tid >> 6;
  const int lane = tid & 63;
  const int n16  = lane & 15;
  const int quad = lane >> 4;

  const long W      = gridDim.x * 4;
  const int  waveId = blockIdx.x * 4 + wave;
  const long last   = nTiles - 1;

  // prefetch tile 0 (asm, registers only) BEFORE the W-stage barrier;
  // the barrier's vmcnt(0) drain completes it — one-time cost.
  floatx4 bufA[8], bufB[8];
  long t = waveId;
  load_tile_asm(bufA, x, (t <= last) ? t : last, lane);

  // stage W' (34816 B) into LDS — once per block
  {
    const uint4* src = (const uint4*)wt;
    uint4* dst = (uint4*)sW;
    for (int i = tid; i < (OUTD * WT_STRIDE * 2) / 16; i += 256) dst[i] = src[i];
  }
  if (tid < OUTD) sBias[tid] = biasEff[tid];

  const float a1 = a1p[0], a2 = a2p[0];
  const float s1 = 128.0f / a1, r1 = a1 * 0.0078125f;  // 32, 1/32 (exact pow2)
  const float s2 = 128.0f / a2, r2 = a2 * 0.0078125f;  // 8, 0.125

  __syncthreads();   // the only barrier

  __bf16* myX = (__bf16*)&sBuf[wave][0];
  // generic->LDS: apertures are 4GB-aligned, low 32 bits == LDS byte offset
  const uint32_t bounceBase = (uint32_t)(uintptr_t)&sBuf[wave][0];

  uint32_t kick = 0;
  // ---- peeled first phase: no stores outstanding yet -> wait vmcnt(8) ----
  if (t <= last) {
    long tn = t + W;
    load_tile_asm(bufB, x, (tn <= last) ? tn : last, lane);
    WAIT_VMCNT(8);                       // bufA's 8 loads done (only bufB younger)
    stage_tile_q(bufA, myX, lane, s1, r1, kick);
    kick = compute_store_tile(myX, bounceBase, sW, sBias, out, t, lane, n16, quad, s2, r2);
    t = tn;
  }
  // ---- steady state: 8 stores + 8 next-loads in flight -> wait vmcnt(16) ----
  while (t <= last) {
    long tn = t + W;
    load_tile_asm(bufA, x, (tn <= last) ? tn : last, lane);
    WAIT_VMCNT(16);                      // bufB's 8 oldest done; stores keep flying
    stage_tile_q(bufB, myX, lane, s1, r1, kick);
    kick = compute_store_tile(myX, bounceBase, sW, sBias, out, t, lane, n16, quad, s2, r2);
    t = tn;
    if (t > last) break;

    tn = t + W;
    load_tile_asm(bufB, x, (tn <= last) ? tn : last, lane);
    WAIT_VMCNT(16);                      // bufA's 8 oldest done
    stage_tile_q(bufA, myX, lane, s1, r1, kick);
    kick = compute_store_tile(myX, bounceBase, sW, sBias, out, t, lane, n16, quad, s2, r2);
    t = tn;
  }
}

extern "C" void kernel_launch(void* const* d_in, const int* in_sizes, int n_in,
                              void* d_out, int out_size, void* d_ws, size_t ws_size,
                              hipStream_t stream) {
  const float* x    = (const float*)d_in[0];
  const float* w    = (const float*)d_in[1];
  const float* bias = (const float*)d_in[2];
  const float* a1   = (const float*)d_in[3];
  const float* a2   = (const float*)d_in[4];
  float* out = (float*)d_out;

  __bf16* wt     = (__bf16*)d_ws;                                   // 34816 B
  float* biasEff = (float*)((char*)d_ws + OUTD * WT_STRIDE * 2);    // +512 B

  const int rows   = in_sizes[0] / INP;   // 262144
  const int nTiles = rows / 16;           // 16384 16-row wave-tiles
  const int grid   = 768;                 // 52736 B LDS -> 3 blocks/CU, 12 waves/CU

  setup_fused<<<64, 256, 0, stream>>>(w, bias, wt, biasEff);
  linlayer_main<<<grid, 256, 0, stream>>>(x, wt, biasEff, a1, a2, out, nTiles);
}

// Round 10
// 249.826 us; speedup vs baseline: 1.0026x; 1.0026x over previous
//
#include <hip/hip_runtime.h>
#include <stdint.h>

#define INP 128
#define OUTD 128
#define WT_STRIDE 136    // k-stride (bf16 elems) for W' rows: +8 pad, keeps ds_read_b128 16B-aligned
#define XT_STRIDE 136    // bf16 elems per x-tile row (272 B, 16B-aligned frag reads)
#define BB_STRIDE 272    // bounce row stride in BYTES (= 136 bf16) — same footprint as x-stage
#define BUF_BYTES 4352   // per-wave union buffer: x-stage 16*136*2 == bounce 16*272
#define NWAVES 8         // waves per block (512 threads): 8 waves amortize ONE sW copy

typedef __bf16 bf16x8 __attribute__((ext_vector_type(8)));
typedef __bf16 bf16x4 __attribute__((ext_vector_type(4)));
typedef float  floatx4 __attribute__((ext_vector_type(4)));
typedef bf16x8 __attribute__((may_alias)) bf16x8_a;
typedef bf16x4 __attribute__((may_alias)) bf16x4_a;

// ---------------- threefry2x32 (bit-exact vs jax._src.prng) ----------------
__device__ __forceinline__ uint32_t rotl32(uint32_t v, uint32_t n) {
  return (v << n) | (v >> (32u - n));
}
__device__ __forceinline__ void tf_round(uint32_t& x0, uint32_t& x1, uint32_t r) {
  x0 += x1; x1 = rotl32(x1, r); x1 ^= x0;
}
__device__ void threefry2x32(uint32_t k0, uint32_t k1, uint32_t c0, uint32_t c1,
                             uint32_t& o0, uint32_t& o1) {
  uint32_t k2 = k0 ^ k1 ^ 0x1BD11BDAu;
  uint32_t x0 = c0 + k0, x1 = c1 + k1;
  tf_round(x0,x1,13); tf_round(x0,x1,15); tf_round(x0,x1,26); tf_round(x0,x1,6);
  x0 += k1; x1 += k2 + 1u;
  tf_round(x0,x1,17); tf_round(x0,x1,29); tf_round(x0,x1,16); tf_round(x0,x1,24);
  x0 += k2; x1 += k0 + 2u;
  tf_round(x0,x1,13); tf_round(x0,x1,15); tf_round(x0,x1,26); tf_round(x0,x1,6);
  x0 += k0; x1 += k1 + 3u;
  tf_round(x0,x1,17); tf_round(x0,x1,29); tf_round(x0,x1,16); tf_round(x0,x1,24);
  x0 += k1; x1 += k2 + 4u;
  tf_round(x0,x1,13); tf_round(x0,x1,15); tf_round(x0,x1,26); tf_round(x0,x1,6);
  x0 += k2; x1 += k0 + 5u;
  o0 = x0; o1 = x1;
}

// Giles single-precision erfinv (matches XLA ErfInv32 family; ~1e-6 abs err)
__device__ float erfinv_giles(float x) {
  float w = -logf((1.0f - x) * (1.0f + x));
  float p;
  if (w < 5.0f) {
    w = w - 2.5f;
    p = 2.81022636e-08f;
    p = fmaf(p, w, 3.43273939e-07f);
    p = fmaf(p, w, -3.5233877e-06f);
    p = fmaf(p, w, -4.39150654e-06f);
    p = fmaf(p, w, 0.00021858087f);
    p = fmaf(p, w, -0.00125372503f);
    p = fmaf(p, w, -0.00417768164f);
    p = fmaf(p, w, 0.246640727f);
    p = fmaf(p, w, 1.50140941f);
  } else {
    w = sqrtf(w) - 3.0f;
    p = -0.000200214257f;
    p = fmaf(p, w, 0.000100950558f);
    p = fmaf(p, w, 0.00134934322f);
    p = fmaf(p, w, -0.00367342844f);
    p = fmaf(p, w, 0.00573950773f);
    p = fmaf(p, w, -0.0076224613f);
    p = fmaf(p, w, 0.00943887047f);
    p = fmaf(p, w, 1.00167406f);
    p = fmaf(p, w, 2.83297682f);
  }
  return p * x;
}

__device__ float normal_from_bits(uint32_t bits) {
  const float lo = -0.999999940395355224609375f;
  uint32_t fb = (bits >> 9) | 0x3F800000u;
  float f = __uint_as_float(fb) - 1.0f;
  float u = fmaxf(lo, f * 2.0f + lo);
  return 1.41421356237309515f * erfinv_giles(u);
}

// partitionable-threefry path (verified bit-exact in earlier rounds)
__device__ __forceinline__ uint32_t rand_bits(uint32_t ka, uint32_t kb, int i) {
  uint32_t o0, o1;
  threefry2x32(ka, kb, 0u, (uint32_t)i, o0, o1);
  return o0 ^ o1;
}

// ---------------- fused setup: one launch, 64 blocks x 256 ----------------
__global__ __launch_bounds__(256) void setup_fused(
    const float* __restrict__ w, const float* __restrict__ bias,
    __bf16* __restrict__ wt, float* __restrict__ biasEff) {
  __shared__ float red[8];
  const int tid = threadIdx.x;

  const floatx4* w4 = (const floatx4*)w;
  float m0 = -3.4e38f, m1 = m0, m2 = m0, m3 = m0;
  #pragma unroll
  for (int it = 0; it < 16; ++it) {
    floatx4 v = w4[it * 256 + tid];
    m0 = fmaxf(m0, v[0]); m1 = fmaxf(m1, v[1]);
    m2 = fmaxf(m2, v[2]); m3 = fmaxf(m3, v[3]);
  }
  float m = fmaxf(fmaxf(m0, m1), fmaxf(m2, m3));
  #pragma unroll
  for (int off = 1; off < 64; off <<= 1) m = fmaxf(m, __shfl_xor(m, off));
  if ((tid & 63) == 0) red[tid >> 6] = m;
  __syncthreads();
  const float wmax = fmaxf(fmaxf(red[0], red[1]), fmaxf(red[2], red[3]));

  // weight noise + quant for this block's 256 weights
  uint32_t k1a, k1b;
  threefry2x32(0u, 1234u, 0u, 0u, k1a, k1b);
  const int i = blockIdx.x * 256 + tid;
  float nrm = normal_from_bits(rand_bits(k1a, k1b, i));
  int r = i >> 7, c = i & 127;   // w[r][c]: r = k (input dim), c = n (output dim)
  float wv = w[i];
  float wq = rintf(fminf(fmaxf(wv * 128.f, -127.f), 127.f)) * 0.0078125f;
  wt[c * WT_STRIDE + r] = (__bf16)(wq + (nrm * wmax) * 0.1f);

  // block 0 (uniform branch): bias max + biasEff
  if (blockIdx.x == 0) {
    float bv = (tid < OUTD) ? bias[tid] : -3.4e38f;
    float bm = bv;
    #pragma unroll
    for (int off = 1; off < 64; off <<= 1) bm = fmaxf(bm, __shfl_xor(bm, off));
    if ((tid & 63) == 0) red[4 + (tid >> 6)] = bm;
    __syncthreads();
    const float bmax = fmaxf(fmaxf(red[4], red[5]), fmaxf(red[6], red[7]));
    if (tid < OUTD) {
      uint32_t k2a, k2b;
      threefry2x32(0u, 1234u, 0u, 1u, k2a, k2b);
      float nrm2 = normal_from_bits(rand_bits(k2a, k2b, tid));
      float bq = rintf(fminf(fmaxf(bv * 128.f, -127.f), 127.f)) * 0.0078125f;
      biasEff[tid] = bq + (nrm2 * bmax) * 0.1f;
    }
  }
}

// ---------------- main ----------------
// R17: OCCUPANCY via sW amortization. Nine rounds established: clean-traffic
// throughput tracks 6.3 TB/s x waves/32 (R7 8w->2.3, R12-16 12w->2.4) and is
// insensitive to per-wave pipelining (depth 0-3 identical), to read source
// (L3-resident dispatches same dur), to store policy (nt null), with all
// pipes <15% busy. The only unpushed axis in the clean regime is resident
// waves, pinned by each 256-thread block carrying a private 34.8KB sW.
// Fix: 512-thread blocks — 8 waves share one sW. LDS/block = 34816 + 8*4352
// + 512 = 70144 -> 2 blocks/CU = 16 waves/CU (was 12). Kernel body identical
// to R16. If dur doesn't move, the wave-law is refuted -> ablation probe next.
__device__ __forceinline__ void load_tile_asm(floatx4 v[8], const float* __restrict__ x,
                                              long tile, int lane) {
  const float* p = x + ((size_t)tile << 11) + lane * 4;   // tile*2048 floats
  #pragma unroll
  for (int k = 0; k < 8; ++k) {
    asm volatile("global_load_dwordx4 %0, %1, off"
                 : "=v"(v[k])
                 : "v"((uint64_t)(uintptr_t)(p + k * 256)));
  }
}

#define WAIT_VMCNT(N) do { \
    asm volatile("s_waitcnt vmcnt(" #N ")"); \
    __builtin_amdgcn_sched_barrier(0); \
  } while (0)

// quantize + deposit bf16: instr k holds rows {2k,2k+1}; lane i -> row 2k+(i>>5), col (i&31)*4
// `kick` is 0 at runtime (asm-produced) — WAR data-dep vs prev tile's bounce reads.
__device__ __forceinline__ void stage_tile_q(const floatx4 v[8], __bf16* __restrict__ myX,
                                             int lane, float s1, float r1, uint32_t kick) {
  const int r0 = lane >> 5;
  const int c  = (lane & 31) * 4 + (int)kick;
  #pragma unroll
  for (int k = 0; k < 8; ++k) {
    bf16x4 q;
    #pragma unroll
    for (int j = 0; j < 4; ++j)
      q[j] = (__bf16)(rintf(fminf(fmaxf(v[k][j] * s1, -127.f), 127.f)) * r1);
    *(bf16x4_a*)&myX[(2 * k + r0) * XT_STRIDE + c] = q;
  }
}

__device__ __forceinline__ uint32_t compute_store_tile(
    const __bf16* __restrict__ myX, uint32_t bounceBase,
    const __bf16* sW, const float* sBias,
    float* __restrict__ out, long tile, int lane, int n16, int quad,
    float s2, float r2) {
  floatx4 acc[8];
  #pragma unroll
  for (int ct = 0; ct < 8; ++ct) acc[ct] = (floatx4)0.0f;

  #pragma unroll
  for (int kc = 0; kc < 4; ++kc) {
    const int kOff = kc * 32 + quad * 8;
    bf16x8 a = *(const bf16x8_a*)&myX[n16 * XT_STRIDE + kOff];   // ds_read_b128, pre-quantized
    #pragma unroll
    for (int ct = 0; ct < 8; ++ct) {
      bf16x8 wfrag = *(const bf16x8*)&sW[(ct * 16 + n16) * WT_STRIDE + kOff];
      // swapped operands: D[i=outcol][j=batchrow] (transposed C/D)
      acc[ct] = __builtin_amdgcn_mfma_f32_16x16x32_bf16(wfrag, a, acc[ct], 0, 0, 0);
    }
  }

  // bias + quant to integer code k in [-127,127]; pack bf16x4 per ct (exact)
  bf16x4 d[8];
  #pragma unroll
  for (int ct = 0; ct < 8; ++ct) {
    const int colBase = ct * 16 + quad * 4;
    #pragma unroll
    for (int r = 0; r < 4; ++r) {
      float h = acc[ct][r] + sBias[colBase + r];
      d[ct][r] = (__bf16)rintf(fminf(fmaxf(h * s2, -127.0f), 127.0f));
    }
  }

  // bounce writes: element (row=n16, col=ct*16+quad*4+r) at row*272 + col*2
  const uint32_t wbase = bounceBase + (uint32_t)n16 * BB_STRIDE + (uint32_t)quad * 8u;
  #pragma unroll
  for (int ct = 0; ct < 8; ++ct)
    asm volatile("ds_write_b64 %0, %1" :: "v"(wbase + (uint32_t)(ct * 32)), "v"(d[ct]));

  // bounce reads: chunk j covers rows {2j,2j+1}; lane i -> row 2j+(i>>5), col (i&31)*4
  const uint32_t rbase = bounceBase + (uint32_t)((lane >> 5) * BB_STRIDE + (lane & 31) * 8);
  bf16x4 rr[8];
  #pragma unroll
  for (int j = 0; j < 8; ++j)
    asm volatile("ds_read_b64 %0, %1" : "=&v"(rr[j]) : "v"(rbase + (uint32_t)(j * 2 * BB_STRIDE)));
  asm volatile("s_waitcnt lgkmcnt(0)");
  __builtin_amdgcn_sched_barrier(0);   // consumers must not hoist above the wait
  // keep write-source regs alive until all bounce ops processed
  asm volatile("" :: "v"(d[0]), "v"(d[1]), "v"(d[2]), "v"(d[3]),
                     "v"(d[4]), "v"(d[5]), "v"(d[6]), "v"(d[7]));

  // lane-contiguous full-line stores: 8 x 1KB per tile (8 full 128-B lines
  // each), non-temporal (kept from R16: null but harmless, avoids L2 churn)
  float* outp = out + ((size_t)tile << 11);
  #pragma unroll
  for (int j = 0; j < 8; ++j) {
    floatx4 o;
    #pragma unroll
    for (int q = 0; q < 4; ++q) o[q] = (float)rr[j][q] * r2;
    __builtin_nontemporal_store(o, (floatx4*)(outp + j * 256 + lane * 4));
  }

  uint32_t kick;
  asm volatile("v_mov_b32 %0, 0" : "=v"(kick));   // opaque 0, ordered after reads
  return kick;
}

// 512 threads, 4 waves/EU -> 2 blocks/CU at 70144 B LDS = 16 waves/CU; VGPR cap 128
__global__ __launch_bounds__(512, 4) void linlayer_main(
    const float* __restrict__ x, const __bf16* __restrict__ wt,
    const float* __restrict__ biasEff, const float* __restrict__ a1p,
    const float* __restrict__ a2p, float* __restrict__ out, int nTiles) {
  __shared__ __attribute__((aligned(16))) __bf16 sW[OUTD * WT_STRIDE];     // 34816 B (shared by 8 waves)
  __shared__ __attribute__((aligned(16))) char  sBuf[NWAVES][BUF_BYTES];   // 34816 B (x-stage ∪ out-bounce)
  __shared__ float sBias[OUTD];                                            //   512 B

  const int tid  = threadIdx.x;
  const int wave = tid >> 6;
  const int lane = tid & 63;
  const int n16  = lane & 15;
  const int quad = lane >> 4;

  const long W      = gridDim.x * NWAVES;
  const int  waveId = blockIdx.x * NWAVES + wave;
  const long last   = nTiles - 1;

  // prefetch tile 0 (asm, registers only) BEFORE the W-stage barrier;
  // the barrier's vmcnt(0) drain completes it — one-time cost.
  floatx4 bufA[8], bufB[8];
  long t = waveId;
  load_tile_asm(bufA, x, (t <= last) ? t : last, lane);

  // stage W' (34816 B) into LDS — once per block, 512 threads cooperate
  {
    const uint4* src = (const uint4*)wt;
    uint4* dst = (uint4*)sW;
    for (int i = tid; i < (OUTD * WT_STRIDE * 2) / 16; i += 512) dst[i] = src[i];
  }
  if (tid < OUTD) sBias[tid] = biasEff[tid];

  const float a1 = a1p[0], a2 = a2p[0];
  const float s1 = 128.0f / a1, r1 = a1 * 0.0078125f;  // 32, 1/32 (exact pow2)
  const float s2 = 128.0f / a2, r2 = a2 * 0.0078125f;  // 8, 0.125

  __syncthreads();   // the only barrier

  __bf16* myX = (__bf16*)&sBuf[wave][0];
  // generic->LDS: apertures are 4GB-aligned, low 32 bits == LDS byte offset
  const uint32_t bounceBase = (uint32_t)(uintptr_t)&sBuf[wave][0];

  uint32_t kick = 0;
  // ---- peeled first phase: no stores outstanding yet -> wait vmcnt(8) ----
  if (t <= last) {
    long tn = t + W;
    load_tile_asm(bufB, x, (tn <= last) ? tn : last, lane);
    WAIT_VMCNT(8);                       // bufA's 8 loads done (only bufB younger)
    stage_tile_q(bufA, myX, lane, s1, r1, kick);
    kick = compute_store_tile(myX, bounceBase, sW, sBias, out, t, lane, n16, quad, s2, r2);
    t = tn;
  }
  // ---- steady state: 8 stores + 8 next-loads in flight -> wait vmcnt(16) ----
  while (t <= last) {
    long tn = t + W;
    load_tile_asm(bufA, x, (tn <= last) ? tn : last, lane);
    WAIT_VMCNT(16);                      // bufB's 8 oldest done; stores keep flying
    stage_tile_q(bufB, myX, lane, s1, r1, kick);
    kick = compute_store_tile(myX, bounceBase, sW, sBias, out, t, lane, n16, quad, s2, r2);
    t = tn;
    if (t > last) break;

    tn = t + W;
    load_tile_asm(bufB, x, (tn <= last) ? tn : last, lane);
    WAIT_VMCNT(16);                      // bufA's 8 oldest done
    stage_tile_q(bufA, myX, lane, s1, r1, kick);
    kick = compute_store_tile(myX, bounceBase, sW, sBias, out, t, lane, n16, quad, s2, r2);
    t = tn;
  }
}

extern "C" void kernel_launch(void* const* d_in, const int* in_sizes, int n_in,
                              void* d_out, int out_size, void* d_ws, size_t ws_size,
                              hipStream_t stream) {
  const float* x    = (const float*)d_in[0];
  const float* w    = (const float*)d_in[1];
  const float* bias = (const float*)d_in[2];
  const float* a1   = (const float*)d_in[3];
  const float* a2   = (const float*)d_in[4];
  float* out = (float*)d_out;

  __bf16* wt     = (__bf16*)d_ws;                                   // 34816 B
  float* biasEff = (float*)((char*)d_ws + OUTD * WT_STRIDE * 2);    // +512 B

  const int rows   = in_sizes[0] / INP;   // 262144
  const int nTiles = rows / 16;           // 16384 16-row wave-tiles
  const int grid   = 512;                 // 512 blocks x 8 waves = 4096 waves, 16/CU

  setup_fused<<<64, 256, 0, stream>>>(w, bias, wt, biasEff);
  linlayer_main<<<grid, 512, 0, stream>>>(x, wt, biasEff, a1, a2, out, nTiles);
}